// Round 20
// baseline (282.898 us; speedup 1.0000x reference)
//
#include <hip/hip_runtime.h>
#include <hip/hip_bf16.h>

#define NATOM  256
#define NBASIS 128
#define NGAUSS 25
#define NFILT  128

typedef float f32x16 __attribute__((ext_vector_type(16)));
typedef short s16x8 __attribute__((ext_vector_type(8)));
typedef unsigned u32x4v __attribute__((ext_vector_type(4)));

union V8 { unsigned u[4]; s16x8 s; u32x4v q; };

__device__ inline unsigned cvt_pk_bf16(float lo, float hi) {
    unsigned d;
    asm("v_cvt_pk_bf16_f32 %0, %1, %2" : "=v"(d) : "v"(lo), "v"(hi));
    return d;
}
__device__ inline unsigned short f2bf(float v) {
    unsigned u = __builtin_bit_cast(unsigned, v);
    u = (u + 0x7FFF + ((u >> 16) & 1)) >> 16;
    return (unsigned short)u;
}
__device__ inline float bf2f(unsigned short u) {
    return __builtin_bit_cast(float, ((unsigned)u) << 16);
}
__device__ inline float fast_tanh(float x) {
    float e = __builtin_amdgcn_exp2f(x * 2.8853900817779268f);
    return 1.0f - 2.0f * __builtin_amdgcn_rcpf(e + 1.0f);
}
// staged-layout byte offset for (chunk-local j=jj, feature f) within a 16KB chunk
__device__ inline int yt_byte(int jj, int f) {
    int jt = jj >> 5, rho = jj & 31;
    int hh = (rho >> 2) & 1, r = (rho & 3) + ((rho >> 3) << 2);
    return (jt << 13) + (hh << 12) + ((((f << 5) + (r << 1)) ^ ((f & 7) << 4)));
}

// ---------------- merged prep: 9 blocks x 128 thr; role = blk%3, l = blk/3 ----------------
__global__ __launch_bounds__(128) void k_prep(const float* __restrict__ fw1_w,
                                              const float* __restrict__ fw1_b,
                                              const float* __restrict__ fw2_w,
                                              const float* __restrict__ fw2_b,
                                              float* __restrict__ w0,
                                              unsigned short* __restrict__ W2sw,
                                              unsigned* __restrict__ a1g) {
    int role = blockIdx.x % 3, l = blockIdx.x / 3;
    int t = threadIdx.x;
    if (role == 0) {
        __shared__ float h[NFILT];
        int f = t;
        float acc = fw1_b[l * NFILT + f];
        #pragma unroll
        for (int g = 0; g < NGAUSS; ++g) {
            float c = (float)g * (5.0f / 24.0f);
            float f0 = __expf(-11.52f * c * c);
            acc += f0 * fw1_w[(l * NGAUSS + g) * NFILT + f];
        }
        h[f] = tanhf(acc);
        __syncthreads();
        float w = fw2_b[l * NFILT + f];
        for (int k = 0; k < NFILT; ++k) w += h[k] * fw2_w[(l * NFILT + k) * NFILT + f];
        w0[l * NFILT + f] = w;
    } else if (role == 1) {
        for (int e = t; e < 16384; e += 128) {
            int k = e >> 7, f = e & 127;
            unsigned short u = f2bf(fw2_w[l * 16384 + (k << 7) + f]);
            int byte = (((f << 8) + (k << 1)) ^ ((f & 7) << 4));
            *(unsigned short*)((char*)W2sw + (size_t)l * 32768 + byte) = u;
        }
    } else {
        if (t < 64) {
            int lane = t;
            int col = lane & 31, hi = lane >> 5;
            for (int idx = 0; idx < 32; ++idx) {
                int mt = idx >> 3, k2 = (idx >> 2) & 1, w = idx & 3;
                int k = (mt << 5) + col;
                int g0 = (k2 << 4) + (hi << 3) + (w << 1);
                int g1 = g0 + 1;
                float v0 = (g0 < 25) ? fw1_w[(l * 25 + g0) * 128 + k]
                                     : ((g0 == 25) ? fw1_b[l * 128 + k] : 0.0f);
                float v1 = (g1 < 25) ? fw1_w[(l * 25 + g1) * 128 + k]
                                     : ((g1 == 25) ? fw1_b[l * 128 + k] : 0.0f);
                a1g[l * 2048 + idx * 64 + lane] = cvt_pk_bf16(v0, v1);
            }
        }
    }
}

// ---------------- layer-0: x = emb[z]; y_t = x@w + b (staged bf16) ----------------
__global__ __launch_bounds__(256) void k_linear0(const float* __restrict__ emb,
                                                 const int* __restrict__ z,
                                                 const float* __restrict__ w,
                                                 const float* __restrict__ bias,
                                                 float* __restrict__ x,
                                                 unsigned short* __restrict__ y_t) {
    int half = threadIdx.x >> 7;
    int f = threadIdx.x & 127;
    int row = blockIdx.x * 2 + half;
    __shared__ float xs[2][NBASIS];
    float xv = emb[z[row] * NBASIS + f];
    x[row * NBASIS + f] = xv;
    xs[half][f] = xv;
    __syncthreads();
    float acc = bias[f];
    #pragma unroll 8
    for (int a = 0; a < NBASIS; ++a) acc += xs[half][a] * w[a * NFILT + f];
    int bb = row >> 8, rr = row & 255;
    int c = rr >> 6, jj = rr & 63;
    char* dst = (char*)y_t + (((size_t)((bb << 2) + c)) << 14) + yt_byte(jj, f);
    *(unsigned short*)dst = f2bf(acc);
}

// ---------------- ysum[b][f] = sum_j y_t[b][j][f], parallel (64 blocks) ----------------
__global__ __launch_bounds__(128) void k_ysum2(const unsigned short* __restrict__ y_t,
                                               float* __restrict__ ysum) {
    int b = blockIdx.x >> 3, fg = blockIdx.x & 7;
    int fl = threadIdx.x & 15, jg = threadIdx.x >> 4;
    int f = (fg << 4) + fl;
    float s = 0.0f;
    for (int q = 0; q < 32; ++q) {
        int j = (jg << 5) + q;
        int c = j >> 6, jj = j & 63;
        const char* p = (const char*)y_t + (((size_t)((b << 2) + c)) << 14) + yt_byte(jj, f);
        s += bf2f(*(const unsigned short*)p);
    }
    __shared__ float red[8][16];
    red[jg][fl] = s;
    __syncthreads();
    if (jg == 0) {
        float tot = 0.0f;
        #pragma unroll
        for (int k = 0; k < 8; ++k) tot += red[k][fl];
        ysum[(b << 7) + f] = tot;
    }
}

// ---------------- cfconv: 8-wave j-split at (512,2) ----------------
// 512 wgs x 512 thr; wave wid: atom i = itile*4 + (wid&3), j-half = wid>>2.
// Each wave: full f-range, 4 j-tiles (its half). Cross-half reduce via LDS
// partner sum. No duplication of GEMM1/tanh. NO (.,4) bounds (miscompiles).
__global__ __launch_bounds__(512, 2) void k_cfconv_mfma(
    const float* __restrict__ pos,
    const unsigned short* __restrict__ y_t,
    const unsigned short* __restrict__ W2sw,
    const unsigned* __restrict__ a1g,
    const float* __restrict__ b2, const float* __restrict__ w0,
    const float* __restrict__ ysum, float* __restrict__ ynew)
{
    __shared__ unsigned short W2t[16384];   // 32KB swizzled bf16
    __shared__ unsigned short ybA[8192];    // 16KB chunk (half 0)
    __shared__ unsigned short ybB[8192];    // 16KB chunk (half 1)
    __shared__ float px[NATOM], py[NATOM], pz[NATOM];

    const int t = threadIdx.x;
    const int b = blockIdx.x >> 6;
    const int ibase = (blockIdx.x & 63) << 2;
    const int wid = t >> 6;
    const int lane = t & 63;
    const int col = lane & 31;
    const int hi = lane >> 5;
    const int half = wid >> 2;
    const int i = ibase + (wid & 3);
    const int swz = (col & 7) << 4;

    // ---- stage W2 (2048 uint4 linear) + positions ----
    {
        const uint4* s4 = (const uint4*)W2sw;
        uint4* d4 = (uint4*)W2t;
        #pragma unroll
        for (int e = 0; e < 4; ++e) d4[t + (e << 9)] = s4[t + (e << 9)];
        if (t < 256) {
            const float* pb = pos + (size_t)b * NATOM * 3;
            px[t] = pb[t * 3 + 0]; py[t] = pb[t * 3 + 1]; pz[t] = pb[t * 3 + 2];
        }
    }

    // ---- A1 frags directly from prepped global (coalesced dword loads) ----
    unsigned a1w[4][2][4];
    #pragma unroll
    for (int mt = 0; mt < 4; ++mt)
      #pragma unroll
      for (int k2 = 0; k2 < 2; ++k2)
        #pragma unroll
        for (int w = 0; w < 4; ++w)
            a1w[mt][k2][w] = a1g[((((mt << 1) + k2) << 2) + w) * 64 + lane];

    __syncthreads();

    const float xi = px[i], yi2 = py[i], zi = pz[i];
    float accv[4] = {0.f, 0.f, 0.f, 0.f};

    for (int s = 0; s < 2; ++s) {
        // stage chunk s -> ybA, chunk s+2 -> ybB (linear uint4 copies)
        {
            const uint4* srcA = (const uint4*)y_t + ((size_t)b << 12) + (s << 10);
            const uint4* srcB = srcA + (2 << 10);
            uint4* dA = (uint4*)ybA; uint4* dB = (uint4*)ybB;
            dA[t] = srcA[t];
            dA[t + 512] = srcA[t + 512];
            dB[t] = srcB[t];
            dB[t + 512] = srcB[t + 512];
        }
        __syncthreads();
        const unsigned short* myb = half ? ybB : ybA;
        const int cs = (half << 1) + s;

        #pragma unroll
        for (int jt = 0; jt < 2; ++jt) {
            int jcol = (cs << 6) + (jt << 5) + col;
            float dxx = px[jcol] - xi, dyy = py[jcol] - yi2, dzz = pz[jcol] - zi;
            float rr = sqrtf(dxx * dxx + dyy * dyy + dzz * dzz);

            // B1 frags: augmented gaussians for this lane's j
            V8 b1f[2];
            #pragma unroll
            for (int k2 = 0; k2 < 2; ++k2)
              #pragma unroll
              for (int w = 0; w < 4; ++w) {
                int g0 = (k2 << 4) + (hi << 3) + (w << 1);
                int g1 = g0 + 1;
                float d0 = rr - (float)g0 * (5.0f / 24.0f);
                float d1v = rr - (float)g1 * (5.0f / 24.0f);
                float v0 = (g0 < 25) ? __builtin_amdgcn_exp2f(-16.619846812f * d0 * d0)
                                     : ((g0 == 25) ? 1.0f : 0.0f);
                float v1 = (g1 < 25) ? __builtin_amdgcn_exp2f(-16.619846812f * d1v * d1v)
                                     : ((g1 == 25) ? 1.0f : 0.0f);
                b1f[k2].u[w] = cvt_pk_bf16(v0, v1);
              }

            // per-mt fused: GEMM1 -> tanh -> pack -> a2 frags
            unsigned a2[8][4];
            #pragma unroll
            for (int mt = 0; mt < 4; ++mt) {
                f32x16 d1;
                #pragma unroll
                for (int q = 0; q < 16; ++q) d1[q] = 0.0f;
                V8 A0, A1;
                #pragma unroll
                for (int w = 0; w < 4; ++w) { A0.u[w] = a1w[mt][0][w]; A1.u[w] = a1w[mt][1][w]; }
                d1 = __builtin_amdgcn_mfma_f32_32x32x16_bf16(A0.s, b1f[0].s, d1, 0, 0, 0);
                d1 = __builtin_amdgcn_mfma_f32_32x32x16_bf16(A1.s, b1f[1].s, d1, 0, 0, 0);
                #pragma unroll
                for (int q = 0; q < 16; ++q) d1[q] = fast_tanh(d1[q]);
                unsigned p[4][2];
                #pragma unroll
                for (int q = 0; q < 4; ++q) {
                    p[q][0] = cvt_pk_bf16(d1[4 * q + 0], d1[4 * q + 1]);
                    p[q][1] = cvt_pk_bf16(d1[4 * q + 2], d1[4 * q + 3]);
                }
                #pragma unroll
                for (int k2 = 0; k2 < 2; ++k2) {
                    unsigned pa0 = p[2 * k2][0], pb0 = p[2 * k2 + 1][0];
                    unsigned pa1 = p[2 * k2][1], pb1 = p[2 * k2 + 1][1];
                    unsigned xa0 = (unsigned)__shfl_xor((int)pa0, 32, 64);
                    unsigned xb0 = (unsigned)__shfl_xor((int)pb0, 32, 64);
                    unsigned xa1 = (unsigned)__shfl_xor((int)pa1, 32, 64);
                    unsigned xb1 = (unsigned)__shfl_xor((int)pb1, 32, 64);
                    int ks = 2 * mt + k2;
                    a2[ks][0] = hi ? xb0 : pa0;
                    a2[ks][1] = hi ? xb1 : pa1;
                    a2[ks][2] = hi ? pb0 : xa0;
                    a2[ks][3] = hi ? pb1 : xa1;
                }
            }

            // GEMM2 + consume with y (full f-range, 4 nt tiles)
            #pragma unroll
            for (int nt = 0; nt < 4; ++nt) {
                int fc = (nt << 5) + col;
                f32x16 c2;
                #pragma unroll
                for (int q = 0; q < 16; ++q) c2[q] = 0.0f;
                #pragma unroll
                for (int ks = 0; ks < 8; ++ks) {
                    int byte = (((fc << 8) + (ks << 5) + (hi << 4)) ^ swz);
                    V8 bf; bf.q = *(const u32x4v*)((const char*)W2t + byte);
                    V8 af;
                    af.u[0] = a2[ks][0]; af.u[1] = a2[ks][1];
                    af.u[2] = a2[ks][2]; af.u[3] = a2[ks][3];
                    c2 = __builtin_amdgcn_mfma_f32_32x32x16_bf16(af.s, bf.s, c2, 0, 0, 0);
                }
                const char* yb = (const char*)myb + (jt << 13) + (hi << 12);
                V8 y0; y0.q = *(const u32x4v*)(yb + (((fc << 5) + 0) ^ swz));
                V8 y1; y1.q = *(const u32x4v*)(yb + (((fc << 5) + 16) ^ swz));
                #pragma unroll
                for (int w = 0; w < 8; ++w) {
                    unsigned uw = (w < 4) ? y0.u[w] : y1.u[w - 4];
                    float ylo = __builtin_bit_cast(float, uw << 16);
                    float yhv = __builtin_bit_cast(float, uw & 0xFFFF0000u);
                    accv[nt] += c2[2 * w] * ylo;
                    accv[nt] += c2[2 * w + 1] * yhv;
                }
            }
        }
        __syncthreads();   // all waves done with bufs before restage / reduce reuse
    }

    // cross-half reduce via LDS (alias ybA)
    float* red = (float*)ybA;
    #pragma unroll
    for (int nt = 0; nt < 4; ++nt) {
        float a = accv[nt] + __shfl_xor(accv[nt], 32, 64);
        if (hi == 0) red[(((wid << 2) + nt) << 5) + col] = a;
    }
    __syncthreads();
    if (half == 0 && hi == 0) {
        #pragma unroll
        for (int nt = 0; nt < 4; ++nt) {
            int f = (nt << 5) + col;
            float a = red[(((wid << 2) + nt) << 5) + col]
                    + red[((((wid + 4) << 2) + nt) << 5) + col];
            int cc = i >> 6, jj = i & 63;
            const char* p = (const char*)y_t + (((size_t)((b << 2) + cc)) << 14) + yt_byte(jj, f);
            float yv = bf2f(*(const unsigned short*)p);
            size_t o = ((size_t)((b << 8) + i) << 7) + f;
            ynew[o] = a + b2[f] * ysum[(b << 7) + f] - yv * w0[f];
        }
    }
}

// ---------------- fused post(+linear | +head-rows) ----------------
__global__ __launch_bounds__(128) void k_postlin(const float* __restrict__ ynew,
                                                 const float* __restrict__ f2w,
                                                 const float* __restrict__ f2b,
                                                 const float* __restrict__ dw,
                                                 const float* __restrict__ db,
                                                 float* __restrict__ x,
                                                 const float* __restrict__ w3,
                                                 const float* __restrict__ b3,
                                                 const float* __restrict__ e2w,
                                                 unsigned short* __restrict__ y_t,
                                                 float* __restrict__ rsum,
                                                 int mode) {
    int row = blockIdx.x;
    int f = threadIdx.x;
    __shared__ float yr[NFILT], y2[NFILT], xs[NFILT];
    __shared__ float ws2[2];
    yr[f] = ynew[row * NFILT + f];
    __syncthreads();
    float acc = f2b[f];
    #pragma unroll 8
    for (int a = 0; a < NFILT; ++a) acc += yr[a] * f2w[a * NBASIS + f];
    y2[f] = tanhf(acc);
    __syncthreads();
    float v = db[f];
    #pragma unroll 8
    for (int a = 0; a < NFILT; ++a) v += y2[a] * dw[a * NBASIS + f];
    float xn = x[row * NBASIS + f] + v;
    x[row * NBASIS + f] = xn;
    xs[f] = xn;
    __syncthreads();
    float acc3 = b3[f];
    #pragma unroll 8
    for (int a = 0; a < NBASIS; ++a) acc3 += xs[a] * w3[a * NFILT + f];
    if (mode == 0) {
        int bb = row >> 8, rr = row & 255;
        int c = rr >> 6, jj = rr & 63;
        char* dst = (char*)y_t + (((size_t)((bb << 2) + c)) << 14) + yt_byte(jj, f);
        *(unsigned short*)dst = f2bf(acc3);
    } else {
        float p = tanhf(acc3) * e2w[f];
        #pragma unroll
        for (int off = 32; off > 0; off >>= 1) p += __shfl_down(p, off, 64);
        if ((f & 63) == 0) ws2[f >> 6] = p;
        __syncthreads();
        if (f == 0) rsum[row] = ws2[0] + ws2[1];
    }
}

__global__ __launch_bounds__(256) void k_head_final(const float* __restrict__ rowsum,
                                                    const float* __restrict__ e2b,
                                                    float* __restrict__ out) {
    int b = blockIdx.x;
    int t = threadIdx.x;
    __shared__ float ws2[4];
    float p = rowsum[b * NATOM + t];
    #pragma unroll
    for (int off = 32; off > 0; off >>= 1) p += __shfl_down(p, off, 64);
    if ((t & 63) == 0) ws2[t >> 6] = p;
    __syncthreads();
    if (t == 0) out[b] = ws2[0] + ws2[1] + ws2[2] + ws2[3] + 256.0f * e2b[0];
}

extern "C" void kernel_launch(void* const* d_in, const int* in_sizes, int n_in,
                              void* d_out, int out_size, void* d_ws, size_t ws_size,
                              hipStream_t stream) {
    const float* pos    = (const float*)d_in[0];
    const int*   z      = (const int*)d_in[1];
    const float* emb    = (const float*)d_in[2];
    const float* fw1_w  = (const float*)d_in[3];
    const float* fw1_b  = (const float*)d_in[4];
    const float* fw2_w  = (const float*)d_in[5];
    const float* fw2_b  = (const float*)d_in[6];
    const float* in2f_w = (const float*)d_in[7];
    const float* in2f_b = (const float*)d_in[8];
    const float* f2o_w  = (const float*)d_in[9];
    const float* f2o_b  = (const float*)d_in[10];
    const float* dns_w  = (const float*)d_in[11];
    const float* dns_b  = (const float*)d_in[12];
    const float* e1w    = (const float*)d_in[13];
    const float* e1b    = (const float*)d_in[14];
    const float* e2w    = (const float*)d_in[15];
    const float* e2b    = (const float*)d_in[16];

    // workspace: ~2.63 MiB total
    float* ws   = (float*)d_ws;
    float* x    = ws;                         // 262144 f
    float* ynew = x + 262144;                 // 262144 f
    float* w0   = ynew + 262144;              // 384 f
    float* rsum = w0 + 384;                   // 2048 f
    float* ysum = rsum + 2048;                // 1024 f
    unsigned* a1g = (unsigned*)(ysum + 1024); // 6144 dw
    unsigned short* W2sw = (unsigned short*)(a1g + 6144);           // 49152 ush
    unsigned short* y_t  = (unsigned short*)((float*)W2sw + 24576); // 262144 ush

    float* out = (float*)d_out;

    k_prep<<<9, 128, 0, stream>>>(fw1_w, fw1_b, fw2_w, fw2_b, w0, W2sw, a1g);
    k_linear0<<<1024, 256, 0, stream>>>(emb, z, in2f_w, in2f_b, x, y_t);
    k_ysum2<<<64, 128, 0, stream>>>(y_t, ysum);

    for (int l = 0; l < 3; ++l) {
        k_cfconv_mfma<<<512, 512, 0, stream>>>(pos, y_t,
                                               W2sw + l * 16384,
                                               a1g + l * 2048,
                                               fw2_b + l * NFILT,
                                               w0 + l * NFILT, ysum, ynew);
        if (l < 2) {
            k_postlin<<<2048, 128, 0, stream>>>(ynew, f2o_w + l * 16384,
                                                f2o_b + l * 128,
                                                dns_w + l * 16384,
                                                dns_b + l * 128, x,
                                                in2f_w + (l + 1) * 16384,
                                                in2f_b + (l + 1) * 128,
                                                e2w, y_t, rsum, 0);
            k_ysum2<<<64, 128, 0, stream>>>(y_t, ysum);
        } else {
            k_postlin<<<2048, 128, 0, stream>>>(ynew, f2o_w + l * 16384,
                                                f2o_b + l * 128,
                                                dns_w + l * 16384,
                                                dns_b + l * 128, x,
                                                e1w, e1b,
                                                e2w, y_t, rsum, 1);
        }
    }
    k_head_final<<<8, 256, 0, stream>>>(rsum, e2b, out);
}

// Round 23
// 258.416 us; speedup vs baseline: 1.0947x; 1.0947x over previous
//
#include <hip/hip_runtime.h>
#include <hip/hip_bf16.h>

#define NATOM  256
#define NBASIS 128
#define NGAUSS 25
#define NFILT  128

typedef float f32x16 __attribute__((ext_vector_type(16)));
typedef short s16x8 __attribute__((ext_vector_type(8)));
typedef unsigned u32x4v __attribute__((ext_vector_type(4)));

union V8 { unsigned u[4]; s16x8 s; u32x4v q; };

__device__ inline unsigned cvt_pk_bf16(float lo, float hi) {
    unsigned d;
    asm("v_cvt_pk_bf16_f32 %0, %1, %2" : "=v"(d) : "v"(lo), "v"(hi));
    return d;
}
__device__ inline unsigned short f2bf(float v) {
    unsigned u = __builtin_bit_cast(unsigned, v);
    u = (u + 0x7FFF + ((u >> 16) & 1)) >> 16;
    return (unsigned short)u;
}
__device__ inline float bf2f(unsigned short u) {
    return __builtin_bit_cast(float, ((unsigned)u) << 16);
}
__device__ inline float fast_tanh(float x) {
    float e = __builtin_amdgcn_exp2f(x * 2.8853900817779268f);
    return 1.0f - 2.0f * __builtin_amdgcn_rcpf(e + 1.0f);
}
// staged-layout byte offset for (chunk-local j=jj, feature f) within a 16KB chunk
__device__ inline int yt_byte(int jj, int f) {
    int jt = jj >> 5, rho = jj & 31;
    int hh = (rho >> 2) & 1, r = (rho & 3) + ((rho >> 3) << 2);
    return (jt << 13) + (hh << 12) + ((((f << 5) + (r << 1)) ^ ((f & 7) << 4)));
}

// ---------------- merged prep: 9 blocks x 128 thr; role = blk%3, l = blk/3 ----------------
__global__ __launch_bounds__(128) void k_prep(const float* __restrict__ fw1_w,
                                              const float* __restrict__ fw1_b,
                                              const float* __restrict__ fw2_w,
                                              const float* __restrict__ fw2_b,
                                              float* __restrict__ w0,
                                              unsigned short* __restrict__ W2sw,
                                              unsigned* __restrict__ a1g) {
    int role = blockIdx.x % 3, l = blockIdx.x / 3;
    int t = threadIdx.x;
    if (role == 0) {
        __shared__ float h[NFILT];
        int f = t;
        float acc = fw1_b[l * NFILT + f];
        #pragma unroll
        for (int g = 0; g < NGAUSS; ++g) {
            float c = (float)g * (5.0f / 24.0f);
            float f0 = __expf(-11.52f * c * c);
            acc += f0 * fw1_w[(l * NGAUSS + g) * NFILT + f];
        }
        h[f] = tanhf(acc);
        __syncthreads();
        float w = fw2_b[l * NFILT + f];
        for (int k = 0; k < NFILT; ++k) w += h[k] * fw2_w[(l * NFILT + k) * NFILT + f];
        w0[l * NFILT + f] = w;
    } else if (role == 1) {
        for (int e = t; e < 16384; e += 128) {
            int k = e >> 7, f = e & 127;
            unsigned short u = f2bf(fw2_w[l * 16384 + (k << 7) + f]);
            int byte = (((f << 8) + (k << 1)) ^ ((f & 7) << 4));
            *(unsigned short*)((char*)W2sw + (size_t)l * 32768 + byte) = u;
        }
    } else {
        if (t < 64) {
            int lane = t;
            int col = lane & 31, hi = lane >> 5;
            for (int idx = 0; idx < 32; ++idx) {
                int mt = idx >> 3, k2 = (idx >> 2) & 1, w = idx & 3;
                int k = (mt << 5) + col;
                int g0 = (k2 << 4) + (hi << 3) + (w << 1);
                int g1 = g0 + 1;
                float v0 = (g0 < 25) ? fw1_w[(l * 25 + g0) * 128 + k]
                                     : ((g0 == 25) ? fw1_b[l * 128 + k] : 0.0f);
                float v1 = (g1 < 25) ? fw1_w[(l * 25 + g1) * 128 + k]
                                     : ((g1 == 25) ? fw1_b[l * 128 + k] : 0.0f);
                a1g[l * 2048 + idx * 64 + lane] = cvt_pk_bf16(v0, v1);
            }
        }
    }
}

// ---------------- layer-0: x = emb[z]; y_t = x@w + b (staged bf16) ----------------
__global__ __launch_bounds__(256) void k_linear0(const float* __restrict__ emb,
                                                 const int* __restrict__ z,
                                                 const float* __restrict__ w,
                                                 const float* __restrict__ bias,
                                                 float* __restrict__ x,
                                                 unsigned short* __restrict__ y_t) {
    int half = threadIdx.x >> 7;
    int f = threadIdx.x & 127;
    int row = blockIdx.x * 2 + half;
    __shared__ float xs[2][NBASIS];
    float xv = emb[z[row] * NBASIS + f];
    x[row * NBASIS + f] = xv;
    xs[half][f] = xv;
    __syncthreads();
    float acc = bias[f];
    #pragma unroll 8
    for (int a = 0; a < NBASIS; ++a) acc += xs[half][a] * w[a * NFILT + f];
    int bb = row >> 8, rr = row & 255;
    int c = rr >> 6, jj = rr & 63;
    char* dst = (char*)y_t + (((size_t)((bb << 2) + c)) << 14) + yt_byte(jj, f);
    *(unsigned short*)dst = f2bf(acc);
}

// ---------------- ysum[b][f] = sum_j y_t[b][j][f], parallel (64 blocks) ----------------
__global__ __launch_bounds__(128) void k_ysum2(const unsigned short* __restrict__ y_t,
                                               float* __restrict__ ysum) {
    int b = blockIdx.x >> 3, fg = blockIdx.x & 7;
    int fl = threadIdx.x & 15, jg = threadIdx.x >> 4;
    int f = (fg << 4) + fl;
    float s = 0.0f;
    for (int q = 0; q < 32; ++q) {
        int j = (jg << 5) + q;
        int c = j >> 6, jj = j & 63;
        const char* p = (const char*)y_t + (((size_t)((b << 2) + c)) << 14) + yt_byte(jj, f);
        s += bf2f(*(const unsigned short*)p);
    }
    __shared__ float red[8][16];
    red[jg][fl] = s;
    __syncthreads();
    if (jg == 0) {
        float tot = 0.0f;
        #pragma unroll
        for (int k = 0; k < 8; ++k) tot += red[k][fl];
        ysum[(b << 7) + f] = tot;
    }
}

// ---------------- cfconv: f-split, (256,2); per-mt fused GEMM1->tanh->pack ----------------
// 1024 wgs x 256 thr; block = (b, itile, fh). Wave = one atom i, f-range
// [fh*64, fh*64+64). Disjoint outputs, plain stores, no atomics, no min-waves-4.
__global__ __launch_bounds__(256, 2) void k_cfconv_mfma(
    const float* __restrict__ pos,
    const unsigned short* __restrict__ y_t,
    const unsigned short* __restrict__ W2sw,
    const unsigned* __restrict__ a1g,
    const float* __restrict__ b2, const float* __restrict__ w0,
    const float* __restrict__ ysum, float* __restrict__ ynew)
{
    __shared__ unsigned short W2t[8192];      // 16KB: own f-half, swizzled bf16
    __shared__ unsigned short ybufS[8192];    // 16KB one 64-j chunk
    __shared__ float px[NATOM], py[NATOM], pz[NATOM];

    const int t = threadIdx.x;
    const int b = blockIdx.x >> 7;
    const int r = blockIdx.x & 127;
    const int itile = r >> 1;
    const int fh = r & 1;
    const int wid = t >> 6;
    const int lane = t & 63;
    const int col = lane & 31;
    const int hi = lane >> 5;
    const int i = (itile << 2) + wid;
    const int swz = (col & 7) << 4;

    // ---- stage W2 f-half (1024 uint4 linear) + positions ----
    {
        const uint4* s4 = (const uint4*)W2sw + (fh << 10);
        uint4* d4 = (uint4*)W2t;
        #pragma unroll
        for (int e = 0; e < 4; ++e) d4[t + (e << 8)] = s4[t + (e << 8)];
        const float* pb = pos + (size_t)b * NATOM * 3;
        px[t] = pb[t * 3 + 0]; py[t] = pb[t * 3 + 1]; pz[t] = pb[t * 3 + 2];
    }

    // ---- A1 frags directly from prepped global (coalesced dword loads) ----
    unsigned a1w[4][2][4];
    #pragma unroll
    for (int mt = 0; mt < 4; ++mt)
      #pragma unroll
      for (int k2 = 0; k2 < 2; ++k2)
        #pragma unroll
        for (int w = 0; w < 4; ++w)
            a1w[mt][k2][w] = a1g[((((mt << 1) + k2) << 2) + w) * 64 + lane];

    __syncthreads();

    const float xi = px[i], yi2 = py[i], zi = pz[i];
    float accv[2] = {0.f, 0.f};

    for (int c = 0; c < 4; ++c) {
        // ---- stage y chunk (64 j) via linear uint4 copy ----
        {
            const uint4* src = (const uint4*)y_t + ((size_t)((b << 2) + c) << 10);
            uint4* dst = (uint4*)ybufS;
            #pragma unroll
            for (int e = 0; e < 4; ++e) dst[t + (e << 8)] = src[t + (e << 8)];
        }
        __syncthreads();

        #pragma unroll
        for (int jt = 0; jt < 2; ++jt) {
            int jcol = (c << 6) + (jt << 5) + col;
            float dxx = px[jcol] - xi, dyy = py[jcol] - yi2, dzz = pz[jcol] - zi;
            float rr = sqrtf(dxx * dxx + dyy * dyy + dzz * dzz);

            // B1 frags: augmented gaussians for this lane's j
            V8 b1f[2];
            #pragma unroll
            for (int k2 = 0; k2 < 2; ++k2)
              #pragma unroll
              for (int w = 0; w < 4; ++w) {
                int g0 = (k2 << 4) + (hi << 3) + (w << 1);
                int g1 = g0 + 1;
                float d0 = rr - (float)g0 * (5.0f / 24.0f);
                float d1v = rr - (float)g1 * (5.0f / 24.0f);
                float v0 = (g0 < 25) ? __builtin_amdgcn_exp2f(-16.619846812f * d0 * d0)
                                     : ((g0 == 25) ? 1.0f : 0.0f);
                float v1 = (g1 < 25) ? __builtin_amdgcn_exp2f(-16.619846812f * d1v * d1v)
                                     : ((g1 == 25) ? 1.0f : 0.0f);
                b1f[k2].u[w] = cvt_pk_bf16(v0, v1);
              }

            // per-mt fused: GEMM1 -> tanh -> pack -> a2 frags (d1 live = 16 regs)
            unsigned a2[8][4];
            #pragma unroll
            for (int mt = 0; mt < 4; ++mt) {
                f32x16 d1;
                #pragma unroll
                for (int q = 0; q < 16; ++q) d1[q] = 0.0f;
                V8 A0, A1;
                #pragma unroll
                for (int w = 0; w < 4; ++w) { A0.u[w] = a1w[mt][0][w]; A1.u[w] = a1w[mt][1][w]; }
                d1 = __builtin_amdgcn_mfma_f32_32x32x16_bf16(A0.s, b1f[0].s, d1, 0, 0, 0);
                d1 = __builtin_amdgcn_mfma_f32_32x32x16_bf16(A1.s, b1f[1].s, d1, 0, 0, 0);
                #pragma unroll
                for (int q = 0; q < 16; ++q) d1[q] = fast_tanh(d1[q]);
                unsigned p[4][2];
                #pragma unroll
                for (int q = 0; q < 4; ++q) {
                    p[q][0] = cvt_pk_bf16(d1[4 * q + 0], d1[4 * q + 1]);
                    p[q][1] = cvt_pk_bf16(d1[4 * q + 2], d1[4 * q + 3]);
                }
                #pragma unroll
                for (int k2 = 0; k2 < 2; ++k2) {
                    unsigned pa0 = p[2 * k2][0], pb0 = p[2 * k2 + 1][0];
                    unsigned pa1 = p[2 * k2][1], pb1 = p[2 * k2 + 1][1];
                    unsigned xa0 = (unsigned)__shfl_xor((int)pa0, 32, 64);
                    unsigned xb0 = (unsigned)__shfl_xor((int)pb0, 32, 64);
                    unsigned xa1 = (unsigned)__shfl_xor((int)pa1, 32, 64);
                    unsigned xb1 = (unsigned)__shfl_xor((int)pb1, 32, 64);
                    int ks = 2 * mt + k2;
                    a2[ks][0] = hi ? xb0 : pa0;
                    a2[ks][1] = hi ? xb1 : pa1;
                    a2[ks][2] = hi ? pb0 : xa0;
                    a2[ks][3] = hi ? pb1 : xa1;
                }
            }

            // GEMM2 + consume with y: only own 2 nt tiles (f = fh*64 + ntl*32 + col)
            #pragma unroll
            for (int ntl = 0; ntl < 2; ++ntl) {
                int fc = (fh << 6) + (ntl << 5) + col;     // global f
                int fcl = (ntl << 5) + col;                // local within W2t half
                f32x16 c2;
                #pragma unroll
                for (int q = 0; q < 16; ++q) c2[q] = 0.0f;
                #pragma unroll
                for (int ks = 0; ks < 8; ++ks) {
                    int byte = (((fcl << 8) + (ks << 5) + (hi << 4)) ^ swz);
                    V8 bf; bf.q = *(const u32x4v*)((const char*)W2t + byte);
                    V8 af;
                    af.u[0] = a2[ks][0]; af.u[1] = a2[ks][1];
                    af.u[2] = a2[ks][2]; af.u[3] = a2[ks][3];
                    c2 = __builtin_amdgcn_mfma_f32_32x32x16_bf16(af.s, bf.s, c2, 0, 0, 0);
                }
                const char* yb = (const char*)ybufS + (jt << 13) + (hi << 12);
                V8 y0; y0.q = *(const u32x4v*)(yb + (((fc << 5) + 0) ^ swz));
                V8 y1; y1.q = *(const u32x4v*)(yb + (((fc << 5) + 16) ^ swz));
                #pragma unroll
                for (int w = 0; w < 8; ++w) {
                    unsigned uw = (w < 4) ? y0.u[w] : y1.u[w - 4];
                    float ylo = __builtin_bit_cast(float, uw << 16);
                    float yhv = __builtin_bit_cast(float, uw & 0xFFFF0000u);
                    accv[ntl] += c2[2 * w] * ylo;
                    accv[ntl] += c2[2 * w + 1] * yhv;
                }
            }
        }
        __syncthreads();   // all waves done with ybufS before restage
    }

    // final cross-half reduce + store own f-slice (disjoint, plain store)
    #pragma unroll
    for (int ntl = 0; ntl < 2; ++ntl) {
        float a = accv[ntl] + __shfl_xor(accv[ntl], 32, 64);
        if (hi == 0) {
            int f = (fh << 6) + (ntl << 5) + col;
            int cc = i >> 6, jj = i & 63;
            const char* p = (const char*)y_t + (((size_t)((b << 2) + cc)) << 14) + yt_byte(jj, f);
            float yv = bf2f(*(const unsigned short*)p);
            size_t o = ((size_t)((b << 8) + i) << 7) + f;
            ynew[o] = a + b2[f] * ysum[(b << 7) + f] - yv * w0[f];
        }
    }
}

// ---------------- fused post(+linear | +head-rows) ----------------
// mode 0: x += dense(tanh(f2out(ynew))); y_t = linear(x, w3, b3) staged
// mode 1: same x update; rsum = sum_f tanh(x@w3+b3)[f]*e2w[f]
__global__ __launch_bounds__(128) void k_postlin(const float* __restrict__ ynew,
                                                 const float* __restrict__ f2w,
                                                 const float* __restrict__ f2b,
                                                 const float* __restrict__ dw,
                                                 const float* __restrict__ db,
                                                 float* __restrict__ x,
                                                 const float* __restrict__ w3,
                                                 const float* __restrict__ b3,
                                                 const float* __restrict__ e2w,
                                                 unsigned short* __restrict__ y_t,
                                                 float* __restrict__ rsum,
                                                 int mode) {
    int row = blockIdx.x;
    int f = threadIdx.x;
    __shared__ float yr[NFILT], y2[NFILT], xs[NFILT];
    __shared__ float ws2[2];
    yr[f] = ynew[row * NFILT + f];
    __syncthreads();
    float acc = f2b[f];
    #pragma unroll 8
    for (int a = 0; a < NFILT; ++a) acc += yr[a] * f2w[a * NBASIS + f];
    y2[f] = tanhf(acc);
    __syncthreads();
    float v = db[f];
    #pragma unroll 8
    for (int a = 0; a < NFILT; ++a) v += y2[a] * dw[a * NBASIS + f];
    float xn = x[row * NBASIS + f] + v;
    x[row * NBASIS + f] = xn;
    xs[f] = xn;
    __syncthreads();
    float acc3 = b3[f];
    #pragma unroll 8
    for (int a = 0; a < NBASIS; ++a) acc3 += xs[a] * w3[a * NFILT + f];
    if (mode == 0) {
        int bb = row >> 8, rr = row & 255;
        int c = rr >> 6, jj = rr & 63;
        char* dst = (char*)y_t + (((size_t)((bb << 2) + c)) << 14) + yt_byte(jj, f);
        *(unsigned short*)dst = f2bf(acc3);
    } else {
        float p = tanhf(acc3) * e2w[f];
        #pragma unroll
        for (int off = 32; off > 0; off >>= 1) p += __shfl_down(p, off, 64);
        if ((f & 63) == 0) ws2[f >> 6] = p;
        __syncthreads();
        if (f == 0) rsum[row] = ws2[0] + ws2[1];
    }
}

__global__ __launch_bounds__(256) void k_head_final(const float* __restrict__ rowsum,
                                                    const float* __restrict__ e2b,
                                                    float* __restrict__ out) {
    int b = blockIdx.x;
    int t = threadIdx.x;
    __shared__ float ws2[4];
    float p = rowsum[b * NATOM + t];
    #pragma unroll
    for (int off = 32; off > 0; off >>= 1) p += __shfl_down(p, off, 64);
    if ((t & 63) == 0) ws2[t >> 6] = p;
    __syncthreads();
    if (t == 0) out[b] = ws2[0] + ws2[1] + ws2[2] + ws2[3] + 256.0f * e2b[0];
}

extern "C" void kernel_launch(void* const* d_in, const int* in_sizes, int n_in,
                              void* d_out, int out_size, void* d_ws, size_t ws_size,
                              hipStream_t stream) {
    const float* pos    = (const float*)d_in[0];
    const int*   z      = (const int*)d_in[1];
    const float* emb    = (const float*)d_in[2];
    const float* fw1_w  = (const float*)d_in[3];
    const float* fw1_b  = (const float*)d_in[4];
    const float* fw2_w  = (const float*)d_in[5];
    const float* fw2_b  = (const float*)d_in[6];
    const float* in2f_w = (const float*)d_in[7];
    const float* in2f_b = (const float*)d_in[8];
    const float* f2o_w  = (const float*)d_in[9];
    const float* f2o_b  = (const float*)d_in[10];
    const float* dns_w  = (const float*)d_in[11];
    const float* dns_b  = (const float*)d_in[12];
    const float* e1w    = (const float*)d_in[13];
    const float* e1b    = (const float*)d_in[14];
    const float* e2w    = (const float*)d_in[15];
    const float* e2b    = (const float*)d_in[16];

    // workspace: ~2.63 MiB total
    float* ws   = (float*)d_ws;
    float* x    = ws;                         // 262144 f
    float* ynew = x + 262144;                 // 262144 f
    float* w0   = ynew + 262144;              // 384 f
    float* rsum = w0 + 384;                   // 2048 f
    float* ysum = rsum + 2048;                // 1024 f
    unsigned* a1g = (unsigned*)(ysum + 1024); // 6144 dw
    unsigned short* W2sw = (unsigned short*)(a1g + 6144);           // 49152 ush
    unsigned short* y_t  = (unsigned short*)((float*)W2sw + 24576); // 262144 ush

    float* out = (float*)d_out;

    k_prep<<<9, 128, 0, stream>>>(fw1_w, fw1_b, fw2_w, fw2_b, w0, W2sw, a1g);
    k_linear0<<<1024, 256, 0, stream>>>(emb, z, in2f_w, in2f_b, x, y_t);
    k_ysum2<<<64, 128, 0, stream>>>(y_t, ysum);

    for (int l = 0; l < 3; ++l) {
        k_cfconv_mfma<<<1024, 256, 0, stream>>>(pos, y_t,
                                                W2sw + l * 16384,
                                                a1g + l * 2048,
                                                fw2_b + l * NFILT,
                                                w0 + l * NFILT, ysum, ynew);
        if (l < 2) {
            k_postlin<<<2048, 128, 0, stream>>>(ynew, f2o_w + l * 16384,
                                                f2o_b + l * 128,
                                                dns_w + l * 16384,
                                                dns_b + l * 128, x,
                                                in2f_w + (l + 1) * 16384,
                                                in2f_b + (l + 1) * 128,
                                                e2w, y_t, rsum, 0);
            k_ysum2<<<64, 128, 0, stream>>>(y_t, ysum);
        } else {
            k_postlin<<<2048, 128, 0, stream>>>(ynew, f2o_w + l * 16384,
                                                f2o_b + l * 128,
                                                dns_w + l * 16384,
                                                dns_b + l * 128, x,
                                                e1w, e1b,
                                                e2w, y_t, rsum, 1);
        }
    }
    k_head_final<<<8, 256, 0, stream>>>(rsum, e2b, out);
}